// Round 1
// baseline (327.197 us; speedup 1.0000x reference)
//
#include <hip/hip_runtime.h>
#include <float.h>

#define N_NODES 50000
#define N_EDGES 600000
#define D 128
#define N_GRAPHS 64
#define SCAN_T 256
#define SCAN_NBLK ((N_NODES + SCAN_T - 1) / SCAN_T)   // 196

typedef __attribute__((ext_vector_type(8))) short short8;   // 8 bf16 = 4 VGPRs
typedef __attribute__((ext_vector_type(4))) float floatx4;

__device__ inline float bf2f(unsigned short h) {
    return __uint_as_float((unsigned)h << 16);
}
__device__ inline unsigned short f2bf(float f) {
    unsigned u = __float_as_uint(f);
    return (unsigned short)((u + 0x7fffu + ((u >> 16) & 1u)) >> 16);   // RNE
}

// ------- fused prep + casts: zero deg, init g, x -> bf16, weights -> Bb --------
// Bb[o][k] row-major-in-k IS the MFMA B-fragment layout (n fixed, k contiguous).

__global__ void cast_prep(const float4* __restrict__ x, ushort4* __restrict__ xb, int n4,
                          const float* __restrict__ Wr0, const float* __restrict__ Wo0,
                          const float* __restrict__ Wr1, const float* __restrict__ Wo1,
                          const float* __restrict__ Wr2, const float* __restrict__ Wo2,
                          unsigned short* __restrict__ B0, unsigned short* __restrict__ B1,
                          unsigned short* __restrict__ B2,
                          int* __restrict__ deg, float* __restrict__ g) {
    int idx = blockIdx.x * 256 + threadIdx.x;
    if (idx < N_NODES) deg[idx] = 0;
    if (idx < N_GRAPHS * D) g[idx] = -FLT_MAX;
    if (idx < n4) {
        float4 v = x[idx];
        ushort4 o;
        o.x = f2bf(v.x); o.y = f2bf(v.y); o.z = f2bf(v.z); o.w = f2bf(v.w);
        xb[idx] = o;
        return;
    }
    int w = idx - n4;                        // 0 .. 3*32768-1
    if (w >= 3 * 128 * 256) return;
    int l = w >> 15;
    int r = w & 32767;
    int o = r >> 8, k = r & 255;
    const float* Wr = (l == 0) ? Wr0 : (l == 1) ? Wr1 : Wr2;
    const float* Wo = (l == 0) ? Wo0 : (l == 1) ? Wo1 : Wo2;
    unsigned short* B = (l == 0) ? B0 : (l == 1) ? B1 : B2;
    float v = (k < 128) ? Wr[o * 128 + k] : Wo[o * 128 + (k - 128)];
    B[r] = f2bf(v);
}

// ---------------- CSR build (once per launch) ----------------------------------

__global__ void count_deg(const int* __restrict__ ei, int* __restrict__ deg) {
    int e = blockIdx.x * 256 + threadIdx.x;
    if (e < N_EDGES) atomicAdd(&deg[ei[N_EDGES + e]], 1);
}

__global__ __launch_bounds__(SCAN_T) void block_sum(const int* __restrict__ deg,
                                                    int* __restrict__ blockSums) {
    __shared__ int s[SCAN_T];
    int tid = threadIdx.x;
    int i = blockIdx.x * SCAN_T + tid;
    s[tid] = (i < N_NODES) ? deg[i] : 0;
    __syncthreads();
    for (int off = SCAN_T / 2; off > 0; off >>= 1) {
        if (tid < off) s[tid] += s[tid + off];
        __syncthreads();
    }
    if (tid == 0) blockSums[blockIdx.x] = s[0];
}

__global__ __launch_bounds__(SCAN_T) void scan_write(const int* __restrict__ deg,
                                                     const int* __restrict__ blockSums,
                                                     int* __restrict__ row_start,
                                                     int* __restrict__ cursor) {
    __shared__ int bs[SCAN_T];
    __shared__ int s[SCAN_T];
    int tid = threadIdx.x;
    bs[tid] = (tid < SCAN_NBLK) ? blockSums[tid] : 0;
    __syncthreads();
    for (int off = 1; off < SCAN_T; off <<= 1) {
        int t = (tid >= off) ? bs[tid - off] : 0;
        __syncthreads();
        bs[tid] += t;
        __syncthreads();
    }
    int myOff = (blockIdx.x == 0) ? 0 : bs[blockIdx.x - 1];
    if (blockIdx.x == 0 && tid == SCAN_T - 1) row_start[N_NODES] = bs[tid];

    int i = blockIdx.x * SCAN_T + tid;
    int v = (i < N_NODES) ? deg[i] : 0;
    s[tid] = v;
    __syncthreads();
    for (int off = 1; off < SCAN_T; off <<= 1) {
        int t = (tid >= off) ? s[tid - off] : 0;
        __syncthreads();
        s[tid] += t;
        __syncthreads();
    }
    if (i < N_NODES) {
        int rs = myOff + s[tid] - v;
        row_start[i] = rs;
        cursor[i]    = rs;
    }
}

__global__ void fill_csr(const int* __restrict__ ei, int* __restrict__ cursor,
                         int* __restrict__ csr_src) {
    int e = blockIdx.x * 256 + threadIdx.x;
    if (e < N_EDGES) {
        int dst = ei[N_EDGES + e];
        int pos = atomicAdd(&cursor[dst], 1);
        csr_src[pos] = ei[e];
    }
}

// ---------------- fused gather: 16 lanes/node, ushort8 rows -> LDS A-tile ------
// sA is [64 rows][128 k] bf16, 16B slots XOR-swizzled: slot = r*16 + (ln ^ (r&7)).
// Store: 4 contiguous rows per wave, each 16B slot written once -> conflict-free.
// Read (MFMA A-frag): per ksL, bank-group = ((ksL*4+quad) ^ (m&7)) -> 8 lanes per
// 4-bank group = balanced, conflict-free.

#define ACC8(u) { a[0] += bf2f((unsigned short)(u)[0]); a[1] += bf2f((unsigned short)(u)[1]); \
                  a[2] += bf2f((unsigned short)(u)[2]); a[3] += bf2f((unsigned short)(u)[3]); \
                  a[4] += bf2f((unsigned short)(u)[4]); a[5] += bf2f((unsigned short)(u)[5]); \
                  a[6] += bf2f((unsigned short)(u)[6]); a[7] += bf2f((unsigned short)(u)[7]); }

__device__ inline void gather_tile(const unsigned short* __restrict__ xb,
                                   const int* __restrict__ row_start,
                                   const int* __restrict__ csr_src,
                                   unsigned short* sA, int row0, int tid)
{
    int grp = tid >> 4;      // 0..15 : node group
    int ln  = tid & 15;      // lane within group: features ln*8 .. ln*8+7
#pragma unroll 1
    for (int pass = 0; pass < 4; ++pass) {
        int r = pass * 16 + grp;             // row within tile, 0..63
        int node = row0 + r;
        float a[8];
#pragma unroll
        for (int i = 0; i < 8; ++i) a[i] = 0.f;
        if (node < N_NODES) {
            int beg = row_start[node];
            int end = row_start[node + 1];
            for (int base = beg; base < end; base += 16) {
                int n = end - base; if (n > 16) n = 16;
                int idx = (ln < n) ? csr_src[base + ln] : 0;   // one coalesced load
                int j = 0;
                for (; j + 7 < n; j += 8) {
                    int s0 = __shfl(idx, j,     16); int s1 = __shfl(idx, j + 1, 16);
                    int s2 = __shfl(idx, j + 2, 16); int s3 = __shfl(idx, j + 3, 16);
                    int s4 = __shfl(idx, j + 4, 16); int s5 = __shfl(idx, j + 5, 16);
                    int s6 = __shfl(idx, j + 6, 16); int s7 = __shfl(idx, j + 7, 16);
                    short8 u0 = *(const short8*)(xb + (size_t)s0 * D + ln * 8);
                    short8 u1 = *(const short8*)(xb + (size_t)s1 * D + ln * 8);
                    short8 u2 = *(const short8*)(xb + (size_t)s2 * D + ln * 8);
                    short8 u3 = *(const short8*)(xb + (size_t)s3 * D + ln * 8);
                    short8 u4 = *(const short8*)(xb + (size_t)s4 * D + ln * 8);
                    short8 u5 = *(const short8*)(xb + (size_t)s5 * D + ln * 8);
                    short8 u6 = *(const short8*)(xb + (size_t)s6 * D + ln * 8);
                    short8 u7 = *(const short8*)(xb + (size_t)s7 * D + ln * 8);
                    ACC8(u0); ACC8(u1); ACC8(u2); ACC8(u3);
                    ACC8(u4); ACC8(u5); ACC8(u6); ACC8(u7);
                }
                for (; j + 3 < n; j += 4) {
                    int s0 = __shfl(idx, j,     16); int s1 = __shfl(idx, j + 1, 16);
                    int s2 = __shfl(idx, j + 2, 16); int s3 = __shfl(idx, j + 3, 16);
                    short8 u0 = *(const short8*)(xb + (size_t)s0 * D + ln * 8);
                    short8 u1 = *(const short8*)(xb + (size_t)s1 * D + ln * 8);
                    short8 u2 = *(const short8*)(xb + (size_t)s2 * D + ln * 8);
                    short8 u3 = *(const short8*)(xb + (size_t)s3 * D + ln * 8);
                    ACC8(u0); ACC8(u1); ACC8(u2); ACC8(u3);
                }
                for (; j < n; ++j) {
                    int s0 = __shfl(idx, j, 16);
                    short8 u0 = *(const short8*)(xb + (size_t)s0 * D + ln * 8);
                    ACC8(u0);
                }
            }
        }
        short8 v;
#pragma unroll
        for (int i = 0; i < 8; ++i) v[i] = (short)f2bf(a[i]);
        int slot = r * 16 + (ln ^ (r & 7));
        *(short8*)((char*)sA + (size_t)slot * 16) = v;
    }
}

// ---------------- B staging: global -> LDS, MFMA-fragment order ----------------
// sB[(ksL*8+t)*64 + lane]: consecutive lanes -> consecutive 16B -> conflict-free.

__device__ inline void stage_b_half(unsigned short* sB, const unsigned short* __restrict__ Bb,
                                    int tid, int h) {
#pragma unroll
    for (int i = 0; i < 8; ++i) {
        int flat = tid + i * 256;            // 0..2047
        int fi = flat >> 6, ln = flat & 63;  // frag idx / lane
        int mm = ln & 15, qq = ln >> 4;
        int ksL = fi >> 3, tt = fi & 7;
        short8 v = *(const short8*)(Bb + (size_t)(tt * 16 + mm) * 256
                                    + (h * 4 + ksL) * 32 + qq * 8);
        *(short8*)(sB + (size_t)flat * 8) = v;
    }
}

// ---------------- fused layer: gather -> MFMA GEMM -> store bf16 ---------------
// O = [agg | x] @ Bb^T + bias (+relu); agg computed in-block into LDS.

__global__ __launch_bounds__(256) void layer_fused(
    const unsigned short* __restrict__ xb, const int* __restrict__ row_start,
    const int* __restrict__ csr_src, const unsigned short* __restrict__ Bb,
    const float* __restrict__ bias, unsigned short* __restrict__ Ob, int relu)
{
    __shared__ unsigned short sA[64 * 128];  // 16 KB swizzled agg tile
    __shared__ unsigned short sB[16384];     // 32 KB B half
    int tid  = threadIdx.x;
    int row0 = blockIdx.x * 64;

    gather_tile(xb, row_start, csr_src, sA, row0, tid);

    int wave = tid >> 6;
    int lane = tid & 63;
    int m    = lane & 15;
    int quad = lane >> 4;

    int arow = row0 + wave * 16 + m;
    if (arow > N_NODES - 1) arow = N_NODES - 1;
    short8 afX[4];                           // x half of A (k = 128..255)
#pragma unroll
    for (int ks = 0; ks < 4; ++ks)
        afX[ks] = *(const short8*)(xb + (size_t)arow * 128 + ks * 32 + quad * 8);

    stage_b_half(sB, Bb, tid, 0);
    __syncthreads();

    short8 afA[4];                           // agg half of A (k = 0..127)
    {
        int r = wave * 16 + m;
#pragma unroll
        for (int ksL = 0; ksL < 4; ++ksL) {
            int slot = r * 16 + ((ksL * 4 + quad) ^ (r & 7));
            afA[ksL] = *(const short8*)((const char*)sA + (size_t)slot * 16);
        }
    }

    floatx4 acc[8];
#pragma unroll
    for (int t = 0; t < 8; ++t) acc[t] = (floatx4){0.f, 0.f, 0.f, 0.f};

#pragma unroll
    for (int ksL = 0; ksL < 4; ++ksL)
#pragma unroll
        for (int t = 0; t < 8; ++t) {
            short8 b = *(const short8*)(sB + (size_t)((ksL * 8 + t) * 64 + lane) * 8);
            acc[t] = __builtin_amdgcn_mfma_f32_16x16x32_bf16(afA[ksL], b, acc[t], 0, 0, 0);
        }
    __syncthreads();
    stage_b_half(sB, Bb, tid, 1);
    __syncthreads();
#pragma unroll
    for (int ksL = 0; ksL < 4; ++ksL)
#pragma unroll
        for (int t = 0; t < 8; ++t) {
            short8 b = *(const short8*)(sB + (size_t)((ksL * 8 + t) * 64 + lane) * 8);
            acc[t] = __builtin_amdgcn_mfma_f32_16x16x32_bf16(afX[ksL], b, acc[t], 0, 0, 0);
        }

#pragma unroll
    for (int t = 0; t < 8; ++t) {
        int col = t * 16 + m;                     // C/D: col=lane&15
        float bv = bias[col];
#pragma unroll
        for (int r = 0; r < 4; ++r) {
            int row = row0 + wave * 16 + quad * 4 + r;   // C/D: row=quad*4+reg
            if (row >= N_NODES) continue;
            float v = acc[t][r] + bv;
            if (relu) v = fmaxf(v, 0.f);
            Ob[(size_t)row * D + col] = f2bf(v);
        }
    }
}

// ---------------- fused layer-3: gather -> GEMM -> pooled max ------------------

struct PoolShared {
    union {
        unsigned short b[16384];     // 32 KB B-half
        float c[64 * 129];           // 33 KB C tile
    };
};

__global__ __launch_bounds__(256) void layer_pool(
    const unsigned short* __restrict__ xb, const int* __restrict__ row_start,
    const int* __restrict__ csr_src, const unsigned short* __restrict__ Bb,
    const float* __restrict__ bias, const int* __restrict__ batch, float* __restrict__ g)
{
    __shared__ unsigned short sA[64 * 128];  // 16 KB swizzled agg tile
    __shared__ PoolShared sh;
    __shared__ int bl[64];
    int tid  = threadIdx.x;
    int row0 = blockIdx.x * 64;

    gather_tile(xb, row_start, csr_src, sA, row0, tid);

    int wave = tid >> 6;
    int lane = tid & 63;
    int m    = lane & 15;
    int quad = lane >> 4;

    int arow = row0 + wave * 16 + m;
    if (arow > N_NODES - 1) arow = N_NODES - 1;
    short8 afX[4];
#pragma unroll
    for (int ks = 0; ks < 4; ++ks)
        afX[ks] = *(const short8*)(xb + (size_t)arow * 128 + ks * 32 + quad * 8);

    if (tid < 64) {
        int grow = row0 + tid;
        bl[tid] = (grow < N_NODES) ? batch[grow] : -1;
    }
    stage_b_half(sh.b, Bb, tid, 0);
    __syncthreads();

    short8 afA[4];
    {
        int r = wave * 16 + m;
#pragma unroll
        for (int ksL = 0; ksL < 4; ++ksL) {
            int slot = r * 16 + ((ksL * 4 + quad) ^ (r & 7));
            afA[ksL] = *(const short8*)((const char*)sA + (size_t)slot * 16);
        }
    }

    floatx4 acc[8];
#pragma unroll
    for (int t = 0; t < 8; ++t) acc[t] = (floatx4){0.f, 0.f, 0.f, 0.f};

#pragma unroll
    for (int ksL = 0; ksL < 4; ++ksL)
#pragma unroll
        for (int t = 0; t < 8; ++t) {
            short8 b = *(const short8*)(sh.b + (size_t)((ksL * 8 + t) * 64 + lane) * 8);
            acc[t] = __builtin_amdgcn_mfma_f32_16x16x32_bf16(afA[ksL], b, acc[t], 0, 0, 0);
        }
    __syncthreads();
    stage_b_half(sh.b, Bb, tid, 1);
    __syncthreads();
#pragma unroll
    for (int ksL = 0; ksL < 4; ++ksL)
#pragma unroll
        for (int t = 0; t < 8; ++t) {
            short8 b = *(const short8*)(sh.b + (size_t)((ksL * 8 + t) * 64 + lane) * 8);
            acc[t] = __builtin_amdgcn_mfma_f32_16x16x32_bf16(afX[ksL], b, acc[t], 0, 0, 0);
        }
    __syncthreads();                         // all sB reads done; reuse as C tile

#pragma unroll
    for (int t = 0; t < 8; ++t) {
        int col = t * 16 + m;
        float bv = bias[col];
#pragma unroll
        for (int r = 0; r < 4; ++r)
            sh.c[(wave * 16 + quad * 4 + r) * 129 + col] = acc[t][r] + bv;
    }
    __syncthreads();

    int nvalid = min(64, N_NODES - row0);
    int b0 = bl[0], b1 = bl[nvalid - 1];     // batch sorted; 1-3 graphs per block
    int col  = tid & 127;
    int rbeg = (tid >> 7) * 32;
    for (int gg = b0; gg <= b1; ++gg) {
        float cur = -FLT_MAX;
#pragma unroll
        for (int r = 0; r < 32; ++r) {
            int rr = rbeg + r;
            float v = (bl[rr] == gg) ? sh.c[rr * 129 + col] : -FLT_MAX;
            cur = fmaxf(cur, v);
        }
        if (cur > -FLT_MAX) {
            float* ad = &g[gg * D + col];
            if (cur >= 0.f) atomicMax((int*)ad, __float_as_int(cur));
            else            atomicMin((unsigned int*)ad, __float_as_uint(cur));
        }
    }
}

// ---------------- head: one wave per graph -------------------------------------

__global__ __launch_bounds__(64) void mlp_head(const float* __restrict__ g,
                         const float* __restrict__ W1, const float* __restrict__ b1,
                         const float* __restrict__ W2, const float* __restrict__ b2,
                         float* __restrict__ out) {
    int gi = blockIdx.x;
    int lane = threadIdx.x;
    float x0 = g[gi * D + lane];
    float x1 = g[gi * D + 64 + lane];
    float o = b2[0];
#pragma unroll
    for (int j = 0; j < 5; ++j) {
        float p = x0 * W1[j * D + lane] + x1 * W1[j * D + 64 + lane];
#pragma unroll
        for (int off = 32; off > 0; off >>= 1) p += __shfl_xor(p, off, 64);
        o += fmaxf(p + b1[j], 0.f) * W2[j];
    }
    if (lane == 0) out[gi] = o;
}

extern "C" void kernel_launch(void* const* d_in, const int* in_sizes, int n_in,
                              void* d_out, int out_size, void* d_ws, size_t ws_size,
                              hipStream_t stream) {
    const float* x     = (const float*)d_in[0];
    const int*   ei    = (const int*)d_in[1];
    const int*   batch = (const int*)d_in[2];
    const float* Wrel[3]  = {(const float*)d_in[3], (const float*)d_in[6], (const float*)d_in[9]};
    const float* brel[3]  = {(const float*)d_in[4], (const float*)d_in[7], (const float*)d_in[10]};
    const float* Wroot[3] = {(const float*)d_in[5], (const float*)d_in[8], (const float*)d_in[11]};
    const float* W1 = (const float*)d_in[12];
    const float* b1 = (const float*)d_in[13];
    const float* W2 = (const float*)d_in[14];
    const float* b2 = (const float*)d_in[15];
    float* out = (float*)d_out;

    char* ws = (char*)d_ws;
    const size_t nodeB16 = (size_t)N_NODES * D * sizeof(unsigned short);   // 12.8 MB
    unsigned short* xb   = (unsigned short*)(ws);
    unsigned short* hb1  = (unsigned short*)(ws + nodeB16);
    unsigned short* hb2  = (unsigned short*)(ws + 2 * nodeB16);
    char* p = ws + 3 * nodeB16;
    unsigned short* Bb0 = (unsigned short*)p;   p += 128 * 256 * sizeof(unsigned short);
    unsigned short* Bb1 = (unsigned short*)p;   p += 128 * 256 * sizeof(unsigned short);
    unsigned short* Bb2 = (unsigned short*)p;   p += 128 * 256 * sizeof(unsigned short);
    float* g        = (float*)p;                p += N_GRAPHS * D * sizeof(float);
    int*   deg      = (int*)p;                  p += N_NODES * sizeof(int);
    int*   row_start= (int*)p;                  p += (N_NODES + 1) * sizeof(int);
    int*   cursor   = (int*)p;                  p += N_NODES * sizeof(int);
    int*   csr_src  = (int*)p;                  p += N_EDGES * sizeof(int);
    int*   blockSums= (int*)p;                  p += SCAN_NBLK * sizeof(int);

    // fused prep + bf16 conversions (runs first; zeroes deg for count_deg)
    const int n4 = N_NODES * D / 4;                       // 1.6M
    const int cast_total = n4 + 3 * 128 * 256;
    cast_prep<<<(cast_total + 255) / 256, 256, 0, stream>>>(
        (const float4*)x, (ushort4*)xb, n4,
        Wrel[0], Wroot[0], Wrel[1], Wroot[1], Wrel[2], Wroot[2],
        Bb0, Bb1, Bb2, deg, g);

    // CSR build (once per call)
    count_deg<<<(N_EDGES + 255) / 256, 256, 0, stream>>>(ei, deg);
    block_sum<<<SCAN_NBLK, SCAN_T, 0, stream>>>(deg, blockSums);
    scan_write<<<SCAN_NBLK, SCAN_T, 0, stream>>>(deg, blockSums, row_start, cursor);
    fill_csr<<<(N_EDGES + 255) / 256, 256, 0, stream>>>(ei, cursor, csr_src);

    const int mgrid = (N_NODES + 63) / 64;                // 782

    layer_fused<<<mgrid, 256, 0, stream>>>(xb,  row_start, csr_src, Bb0, brel[0], hb1, 1);
    layer_fused<<<mgrid, 256, 0, stream>>>(hb1, row_start, csr_src, Bb1, brel[1], hb2, 1);
    layer_pool <<<mgrid, 256, 0, stream>>>(hb2, row_start, csr_src, Bb2, brel[2], batch, g);

    mlp_head<<<N_GRAPHS, 64, 0, stream>>>(g, W1, b1, W2, b2, out);
}

// Round 2
// 321.770 us; speedup vs baseline: 1.0169x; 1.0169x over previous
//
#include <hip/hip_runtime.h>
#include <float.h>

#define N_NODES 50000
#define N_EDGES 600000
#define D 128
#define N_GRAPHS 64
#define SCAN_T 256
#define SCAN_NBLK ((N_NODES + SCAN_T - 1) / SCAN_T)   // 196

typedef __attribute__((ext_vector_type(8))) short short8;   // 8 bf16 = 4 VGPRs
typedef __attribute__((ext_vector_type(4))) float floatx4;

__device__ inline float bf2f(unsigned short h) {
    return __uint_as_float((unsigned)h << 16);
}
__device__ inline unsigned short f2bf(float f) {
    unsigned u = __float_as_uint(f);
    return (unsigned short)((u + 0x7fffu + ((u >> 16) & 1u)) >> 16);   // RNE
}

// ------- fused prep + casts: zero deg, init g, x -> half-tables, weights -> Bb -
// Node features are stored as TWO half-tables [N][64] (6.4 MB each) so the
// random-access gather works against a working set that nearly fits one XCD's
// 4 MB L2, and each half-row is exactly one 128 B cache line.
// Bb[o][k] row-major-in-k IS the MFMA B-fragment layout (n fixed, k contiguous).

__global__ void cast_prep(const float4* __restrict__ x,
                          ushort4* __restrict__ xb0, ushort4* __restrict__ xb1, int n4,
                          const float* __restrict__ Wr0, const float* __restrict__ Wo0,
                          const float* __restrict__ Wr1, const float* __restrict__ Wo1,
                          const float* __restrict__ Wr2, const float* __restrict__ Wo2,
                          unsigned short* __restrict__ B0, unsigned short* __restrict__ B1,
                          unsigned short* __restrict__ B2,
                          int* __restrict__ deg, float* __restrict__ g) {
    int idx = blockIdx.x * 256 + threadIdx.x;
    if (idx < N_NODES) deg[idx] = 0;
    if (idx < N_GRAPHS * D) g[idx] = -FLT_MAX;
    if (idx < n4) {
        float4 v = x[idx];
        ushort4 o;
        o.x = f2bf(v.x); o.y = f2bf(v.y); o.z = f2bf(v.z); o.w = f2bf(v.w);
        int node = idx >> 5;                 // 32 ushort4-quads per 128-wide row
        int q    = idx & 31;                 // quad within row (features q*4..q*4+3)
        ushort4* dst = (q < 16) ? xb0 : xb1;
        dst[(size_t)node * 16 + (q & 15)] = o;
        return;
    }
    int w = idx - n4;                        // 0 .. 3*32768-1
    if (w >= 3 * 128 * 256) return;
    int l = w >> 15;
    int r = w & 32767;
    int o = r >> 8, k = r & 255;
    const float* Wr = (l == 0) ? Wr0 : (l == 1) ? Wr1 : Wr2;
    const float* Wo = (l == 0) ? Wo0 : (l == 1) ? Wo1 : Wo2;
    unsigned short* B = (l == 0) ? B0 : (l == 1) ? B1 : B2;
    float v = (k < 128) ? Wr[o * 128 + k] : Wo[o * 128 + (k - 128)];
    B[r] = f2bf(v);
}

// ---------------- CSR build (once per launch) ----------------------------------

__global__ void count_deg(const int* __restrict__ ei, int* __restrict__ deg) {
    int e = blockIdx.x * 256 + threadIdx.x;
    if (e < N_EDGES) atomicAdd(&deg[ei[N_EDGES + e]], 1);
}

__global__ __launch_bounds__(SCAN_T) void block_sum(const int* __restrict__ deg,
                                                    int* __restrict__ blockSums) {
    __shared__ int s[SCAN_T];
    int tid = threadIdx.x;
    int i = blockIdx.x * SCAN_T + tid;
    s[tid] = (i < N_NODES) ? deg[i] : 0;
    __syncthreads();
    for (int off = SCAN_T / 2; off > 0; off >>= 1) {
        if (tid < off) s[tid] += s[tid + off];
        __syncthreads();
    }
    if (tid == 0) blockSums[blockIdx.x] = s[0];
}

__global__ __launch_bounds__(SCAN_T) void scan_write(const int* __restrict__ deg,
                                                     const int* __restrict__ blockSums,
                                                     int* __restrict__ row_start,
                                                     int* __restrict__ cursor) {
    __shared__ int bs[SCAN_T];
    __shared__ int s[SCAN_T];
    int tid = threadIdx.x;
    bs[tid] = (tid < SCAN_NBLK) ? blockSums[tid] : 0;
    __syncthreads();
    for (int off = 1; off < SCAN_T; off <<= 1) {
        int t = (tid >= off) ? bs[tid - off] : 0;
        __syncthreads();
        bs[tid] += t;
        __syncthreads();
    }
    int myOff = (blockIdx.x == 0) ? 0 : bs[blockIdx.x - 1];
    if (blockIdx.x == 0 && tid == SCAN_T - 1) row_start[N_NODES] = bs[tid];

    int i = blockIdx.x * SCAN_T + tid;
    int v = (i < N_NODES) ? deg[i] : 0;
    s[tid] = v;
    __syncthreads();
    for (int off = 1; off < SCAN_T; off <<= 1) {
        int t = (tid >= off) ? s[tid - off] : 0;
        __syncthreads();
        s[tid] += t;
        __syncthreads();
    }
    if (i < N_NODES) {
        int rs = myOff + s[tid] - v;
        row_start[i] = rs;
        cursor[i]    = rs;
    }
}

__global__ void fill_csr(const int* __restrict__ ei, int* __restrict__ cursor,
                         int* __restrict__ csr_src) {
    int e = blockIdx.x * 256 + threadIdx.x;
    if (e < N_EDGES) {
        int dst = ei[N_EDGES + e];
        int pos = atomicAdd(&cursor[dst], 1);
        csr_src[pos] = ei[e];
    }
}

// ---------------- gather over ONE half-table ------------------------------------
// 8 lanes/node, short8 per lane: one neighbor half-row = 8 lanes x 16 B = one
// 128 B cache line. Two grid-wide launches (h=0 then h=1) keep the active
// working set at 6.4 MB for the whole launch -> ~2x the per-XCD L2 hit rate of
// a 12.8 MB table, and half the miss-queue occupancy per row.

#define ACC8(u) { a[0] += bf2f((unsigned short)(u)[0]); a[1] += bf2f((unsigned short)(u)[1]); \
                  a[2] += bf2f((unsigned short)(u)[2]); a[3] += bf2f((unsigned short)(u)[3]); \
                  a[4] += bf2f((unsigned short)(u)[4]); a[5] += bf2f((unsigned short)(u)[5]); \
                  a[6] += bf2f((unsigned short)(u)[6]); a[7] += bf2f((unsigned short)(u)[7]); }

__global__ __launch_bounds__(256) void gather_half(
    const unsigned short* __restrict__ xh,    // [N][64] half-table
    const int* __restrict__ row_start, const int* __restrict__ csr_src,
    unsigned short* __restrict__ aggh)        // [N][64] half-agg out (bf16)
{
    int grp  = threadIdx.x >> 3;              // 32 node-groups per block
    int ln   = threadIdx.x & 7;               // features ln*8 .. ln*8+7
    int node = blockIdx.x * 32 + grp;
    if (node >= N_NODES) return;
    int beg = row_start[node];
    int end = row_start[node + 1];

    float a[8];
#pragma unroll
    for (int i = 0; i < 8; ++i) a[i] = 0.f;

    for (int base = beg; base < end; base += 8) {
        int n = end - base; if (n > 8) n = 8;
        int idx = (ln < n) ? csr_src[base + ln] : 0;   // one coalesced 32 B load
        int j = 0;
        for (; j + 7 < n; j += 8) {                    // full batch: 8 lines in flight
            int s0 = __shfl(idx, 0, 8); int s1 = __shfl(idx, 1, 8);
            int s2 = __shfl(idx, 2, 8); int s3 = __shfl(idx, 3, 8);
            int s4 = __shfl(idx, 4, 8); int s5 = __shfl(idx, 5, 8);
            int s6 = __shfl(idx, 6, 8); int s7 = __shfl(idx, 7, 8);
            short8 u0 = *(const short8*)(xh + (size_t)s0 * 64 + ln * 8);
            short8 u1 = *(const short8*)(xh + (size_t)s1 * 64 + ln * 8);
            short8 u2 = *(const short8*)(xh + (size_t)s2 * 64 + ln * 8);
            short8 u3 = *(const short8*)(xh + (size_t)s3 * 64 + ln * 8);
            short8 u4 = *(const short8*)(xh + (size_t)s4 * 64 + ln * 8);
            short8 u5 = *(const short8*)(xh + (size_t)s5 * 64 + ln * 8);
            short8 u6 = *(const short8*)(xh + (size_t)s6 * 64 + ln * 8);
            short8 u7 = *(const short8*)(xh + (size_t)s7 * 64 + ln * 8);
            ACC8(u0); ACC8(u1); ACC8(u2); ACC8(u3);
            ACC8(u4); ACC8(u5); ACC8(u6); ACC8(u7);
        }
        for (; j + 3 < n; j += 4) {
            int s0 = __shfl(idx, j,     8); int s1 = __shfl(idx, j + 1, 8);
            int s2 = __shfl(idx, j + 2, 8); int s3 = __shfl(idx, j + 3, 8);
            short8 u0 = *(const short8*)(xh + (size_t)s0 * 64 + ln * 8);
            short8 u1 = *(const short8*)(xh + (size_t)s1 * 64 + ln * 8);
            short8 u2 = *(const short8*)(xh + (size_t)s2 * 64 + ln * 8);
            short8 u3 = *(const short8*)(xh + (size_t)s3 * 64 + ln * 8);
            ACC8(u0); ACC8(u1); ACC8(u2); ACC8(u3);
        }
        for (; j < n; ++j) {
            int s0 = __shfl(idx, j, 8);
            short8 u0 = *(const short8*)(xh + (size_t)s0 * 64 + ln * 8);
            ACC8(u0);
        }
    }
    short8 r;
#pragma unroll
    for (int i = 0; i < 8; ++i) r[i] = (short)f2bf(a[i]);
    *(short8*)(aggh + (size_t)node * 64 + ln * 8) = r;
}

// ---------------- B staging: global -> LDS, MFMA-fragment order ----------------
// sB[(ksL*8+t)*64 + lane]: consecutive lanes -> consecutive 16B -> conflict-free.

__device__ inline void stage_b_half(unsigned short* sB, const unsigned short* __restrict__ Bb,
                                    int tid, int h) {
#pragma unroll
    for (int i = 0; i < 8; ++i) {
        int flat = tid + i * 256;            // 0..2047
        int fi = flat >> 6, ln = flat & 63;  // frag idx / lane
        int mm = ln & 15, qq = ln >> 4;
        int ksL = fi >> 3, tt = fi & 7;
        short8 v = *(const short8*)(Bb + (size_t)(tt * 16 + mm) * 256
                                    + (h * 4 + ksL) * 32 + qq * 8);
        *(short8*)(sB + (size_t)flat * 8) = v;
    }
}

// ---------------- MFMA GEMM: O = [agg|x] @ Bb^T + bias (+relu) -----------------
// A and O live in half-tables: k 0..63 -> agg0, 64..127 -> agg1,
// 128..191 -> x0, 192..255 -> x1.  af[ks] covers k = ks*32 .. +31.

__global__ __launch_bounds__(256) void gemm_mfma(
    const unsigned short* __restrict__ agg0, const unsigned short* __restrict__ agg1,
    const unsigned short* __restrict__ x0,   const unsigned short* __restrict__ x1,
    const unsigned short* __restrict__ Bb, const float* __restrict__ bias,
    unsigned short* __restrict__ O0, unsigned short* __restrict__ O1, int relu)
{
    __shared__ unsigned short sB[16384];     // 32 KB
    int tid  = threadIdx.x;
    int wave = tid >> 6;
    int lane = tid & 63;
    int m    = lane & 15;
    int quad = lane >> 4;
    int row0 = blockIdx.x * 64 + wave * 16;

    int arow = row0 + m;
    if (arow > N_NODES - 1) arow = N_NODES - 1;

    short8 af[8];
#pragma unroll
    for (int ks = 0; ks < 8; ++ks) {
        const unsigned short* Asrc =
            (ks < 2) ? agg0 : (ks < 4) ? agg1 : (ks < 6) ? x0 : x1;
        af[ks] = *(const short8*)(Asrc + (size_t)arow * 64 + (ks & 1) * 32 + quad * 8);
    }

    floatx4 acc[8];
#pragma unroll
    for (int t = 0; t < 8; ++t) acc[t] = (floatx4){0.f, 0.f, 0.f, 0.f};

    stage_b_half(sB, Bb, tid, 0);
    __syncthreads();
#pragma unroll
    for (int ksL = 0; ksL < 4; ++ksL)
#pragma unroll
        for (int t = 0; t < 8; ++t) {
            short8 b = *(const short8*)(sB + (size_t)((ksL * 8 + t) * 64 + lane) * 8);
            acc[t] = __builtin_amdgcn_mfma_f32_16x16x32_bf16(af[ksL], b, acc[t], 0, 0, 0);
        }
    __syncthreads();
    stage_b_half(sB, Bb, tid, 1);
    __syncthreads();
#pragma unroll
    for (int ksL = 0; ksL < 4; ++ksL)
#pragma unroll
        for (int t = 0; t < 8; ++t) {
            short8 b = *(const short8*)(sB + (size_t)((ksL * 8 + t) * 64 + lane) * 8);
            acc[t] = __builtin_amdgcn_mfma_f32_16x16x32_bf16(af[4 + ksL], b, acc[t], 0, 0, 0);
        }

#pragma unroll
    for (int t = 0; t < 8; ++t) {
        int col = t * 16 + m;                     // C/D: col=lane&15
        float bv = bias[col];
        unsigned short* Oh = (t < 4) ? O0 : O1;
#pragma unroll
        for (int r = 0; r < 4; ++r) {
            int row = row0 + quad * 4 + r;        // C/D: row=quad*4+reg
            if (row >= N_NODES) continue;
            float v = acc[t][r] + bv;
            if (relu) v = fmaxf(v, 0.f);
            Oh[(size_t)row * 64 + (col & 63)] = f2bf(v);
        }
    }
}

// ---------------- layer-3 GEMM with fused pooled max ---------------------------

struct PoolShared {
    union {
        unsigned short b[16384];     // 32 KB B-half
        float c[64 * 129];           // 33 KB C tile
    };
};

__global__ __launch_bounds__(256) void gemm_pool(
    const unsigned short* __restrict__ agg0, const unsigned short* __restrict__ agg1,
    const unsigned short* __restrict__ x0,   const unsigned short* __restrict__ x1,
    const unsigned short* __restrict__ Bb, const float* __restrict__ bias,
    const int* __restrict__ batch, float* __restrict__ g)
{
    __shared__ PoolShared sh;
    __shared__ int bl[64];
    int tid  = threadIdx.x;
    int wave = tid >> 6;
    int lane = tid & 63;
    int m    = lane & 15;
    int quad = lane >> 4;
    int row0 = blockIdx.x * 64;

    int arow = row0 + wave * 16 + m;
    if (arow > N_NODES - 1) arow = N_NODES - 1;

    short8 af[8];
#pragma unroll
    for (int ks = 0; ks < 8; ++ks) {
        const unsigned short* Asrc =
            (ks < 2) ? agg0 : (ks < 4) ? agg1 : (ks < 6) ? x0 : x1;
        af[ks] = *(const short8*)(Asrc + (size_t)arow * 64 + (ks & 1) * 32 + quad * 8);
    }

    floatx4 acc[8];
#pragma unroll
    for (int t = 0; t < 8; ++t) acc[t] = (floatx4){0.f, 0.f, 0.f, 0.f};

    if (tid < 64) {
        int grow = row0 + tid;
        bl[tid] = (grow < N_NODES) ? batch[grow] : -1;
    }
    stage_b_half(sh.b, Bb, tid, 0);
    __syncthreads();
#pragma unroll
    for (int ksL = 0; ksL < 4; ++ksL)
#pragma unroll
        for (int t = 0; t < 8; ++t) {
            short8 b = *(const short8*)(sh.b + (size_t)((ksL * 8 + t) * 64 + lane) * 8);
            acc[t] = __builtin_amdgcn_mfma_f32_16x16x32_bf16(af[ksL], b, acc[t], 0, 0, 0);
        }
    __syncthreads();
    stage_b_half(sh.b, Bb, tid, 1);
    __syncthreads();
#pragma unroll
    for (int ksL = 0; ksL < 4; ++ksL)
#pragma unroll
        for (int t = 0; t < 8; ++t) {
            short8 b = *(const short8*)(sh.b + (size_t)((ksL * 8 + t) * 64 + lane) * 8);
            acc[t] = __builtin_amdgcn_mfma_f32_16x16x32_bf16(af[4 + ksL], b, acc[t], 0, 0, 0);
        }
    __syncthreads();                         // all sB reads done; reuse as C tile

#pragma unroll
    for (int t = 0; t < 8; ++t) {
        int col = t * 16 + m;
        float bv = bias[col];
#pragma unroll
        for (int r = 0; r < 4; ++r)
            sh.c[(wave * 16 + quad * 4 + r) * 129 + col] = acc[t][r] + bv;
    }
    __syncthreads();

    int nvalid = min(64, N_NODES - row0);
    int b0 = bl[0], b1 = bl[nvalid - 1];     // batch sorted; 1-3 graphs per block
    int col  = tid & 127;
    int rbeg = (tid >> 7) * 32;
    for (int gg = b0; gg <= b1; ++gg) {
        float cur = -FLT_MAX;
#pragma unroll
        for (int r = 0; r < 32; ++r) {
            int rr = rbeg + r;
            float v = (bl[rr] == gg) ? sh.c[rr * 129 + col] : -FLT_MAX;
            cur = fmaxf(cur, v);
        }
        if (cur > -FLT_MAX) {
            float* ad = &g[gg * D + col];
            if (cur >= 0.f) atomicMax((int*)ad, __float_as_int(cur));
            else            atomicMin((unsigned int*)ad, __float_as_uint(cur));
        }
    }
}

// ---------------- head: one wave per graph -------------------------------------

__global__ __launch_bounds__(64) void mlp_head(const float* __restrict__ g,
                         const float* __restrict__ W1, const float* __restrict__ b1,
                         const float* __restrict__ W2, const float* __restrict__ b2,
                         float* __restrict__ out) {
    int gi = blockIdx.x;
    int lane = threadIdx.x;
    float x0 = g[gi * D + lane];
    float x1 = g[gi * D + 64 + lane];
    float o = b2[0];
#pragma unroll
    for (int j = 0; j < 5; ++j) {
        float p = x0 * W1[j * D + lane] + x1 * W1[j * D + 64 + lane];
#pragma unroll
        for (int off = 32; off > 0; off >>= 1) p += __shfl_xor(p, off, 64);
        o += fmaxf(p + b1[j], 0.f) * W2[j];
    }
    if (lane == 0) out[gi] = o;
}

extern "C" void kernel_launch(void* const* d_in, const int* in_sizes, int n_in,
                              void* d_out, int out_size, void* d_ws, size_t ws_size,
                              hipStream_t stream) {
    const float* x     = (const float*)d_in[0];
    const int*   ei    = (const int*)d_in[1];
    const int*   batch = (const int*)d_in[2];
    const float* Wrel[3]  = {(const float*)d_in[3], (const float*)d_in[6], (const float*)d_in[9]};
    const float* brel[3]  = {(const float*)d_in[4], (const float*)d_in[7], (const float*)d_in[10]};
    const float* Wroot[3] = {(const float*)d_in[5], (const float*)d_in[8], (const float*)d_in[11]};
    const float* W1 = (const float*)d_in[12];
    const float* b1 = (const float*)d_in[13];
    const float* W2 = (const float*)d_in[14];
    const float* b2 = (const float*)d_in[15];
    float* out = (float*)d_out;

    char* ws = (char*)d_ws;
    const size_t halfB = (size_t)N_NODES * 64 * sizeof(unsigned short);   // 6.4 MB
    unsigned short* xb0  = (unsigned short*)(ws);
    unsigned short* xb1  = (unsigned short*)(ws + 1 * halfB);
    unsigned short* hb10 = (unsigned short*)(ws + 2 * halfB);
    unsigned short* hb11 = (unsigned short*)(ws + 3 * halfB);
    unsigned short* hb20 = (unsigned short*)(ws + 4 * halfB);
    unsigned short* hb21 = (unsigned short*)(ws + 5 * halfB);
    unsigned short* ag0  = (unsigned short*)(ws + 6 * halfB);
    unsigned short* ag1  = (unsigned short*)(ws + 7 * halfB);
    char* p = ws + 8 * halfB;
    unsigned short* Bb0 = (unsigned short*)p;   p += 128 * 256 * sizeof(unsigned short);
    unsigned short* Bb1 = (unsigned short*)p;   p += 128 * 256 * sizeof(unsigned short);
    unsigned short* Bb2 = (unsigned short*)p;   p += 128 * 256 * sizeof(unsigned short);
    float* g        = (float*)p;                p += N_GRAPHS * D * sizeof(float);
    int*   deg      = (int*)p;                  p += N_NODES * sizeof(int);
    int*   row_start= (int*)p;                  p += (N_NODES + 1) * sizeof(int);
    int*   cursor   = (int*)p;                  p += N_NODES * sizeof(int);
    int*   csr_src  = (int*)p;                  p += N_EDGES * sizeof(int);
    int*   blockSums= (int*)p;                  p += SCAN_NBLK * sizeof(int);

    // fused prep + bf16 conversions (runs first; zeroes deg for count_deg)
    const int n4 = N_NODES * D / 4;                       // 1.6M
    const int cast_total = n4 + 3 * 128 * 256;
    cast_prep<<<(cast_total + 255) / 256, 256, 0, stream>>>(
        (const float4*)x, (ushort4*)xb0, (ushort4*)xb1, n4,
        Wrel[0], Wroot[0], Wrel[1], Wroot[1], Wrel[2], Wroot[2],
        Bb0, Bb1, Bb2, deg, g);

    // CSR build (once per call)
    count_deg<<<(N_EDGES + 255) / 256, 256, 0, stream>>>(ei, deg);
    block_sum<<<SCAN_NBLK, SCAN_T, 0, stream>>>(deg, blockSums);
    scan_write<<<SCAN_NBLK, SCAN_T, 0, stream>>>(deg, blockSums, row_start, cursor);
    fill_csr<<<(N_EDGES + 255) / 256, 256, 0, stream>>>(ei, cursor, csr_src);

    const int ggrid = (N_NODES + 31) / 32;                // 1563
    const int mgrid = (N_NODES + 63) / 64;                // 782

    // layer 1
    gather_half<<<ggrid, 256, 0, stream>>>(xb0, row_start, csr_src, ag0);
    gather_half<<<ggrid, 256, 0, stream>>>(xb1, row_start, csr_src, ag1);
    gemm_mfma<<<mgrid, 256, 0, stream>>>(ag0, ag1, xb0, xb1, Bb0, brel[0], hb10, hb11, 1);
    // layer 2
    gather_half<<<ggrid, 256, 0, stream>>>(hb10, row_start, csr_src, ag0);
    gather_half<<<ggrid, 256, 0, stream>>>(hb11, row_start, csr_src, ag1);
    gemm_mfma<<<mgrid, 256, 0, stream>>>(ag0, ag1, hb10, hb11, Bb1, brel[1], hb20, hb21, 1);
    // layer 3 + pool
    gather_half<<<ggrid, 256, 0, stream>>>(hb20, row_start, csr_src, ag0);
    gather_half<<<ggrid, 256, 0, stream>>>(hb21, row_start, csr_src, ag1);
    gemm_pool<<<mgrid, 256, 0, stream>>>(ag0, ag1, hb20, hb21, Bb2, brel[2], batch, g);

    mlp_head<<<N_GRAPHS, 64, 0, stream>>>(g, W1, b1, W2, b2, out);
}

// Round 3
// 320.391 us; speedup vs baseline: 1.0212x; 1.0043x over previous
//
#include <hip/hip_runtime.h>
#include <float.h>

#define N_NODES 50000
#define N_EDGES 600000
#define D 128
#define N_GRAPHS 64
#define SCAN_T 256
#define SCAN_NBLK ((N_NODES + SCAN_T - 1) / SCAN_T)   // 196

typedef __attribute__((ext_vector_type(8))) short short8;   // 8 bf16 = 4 VGPRs
typedef __attribute__((ext_vector_type(4))) float floatx4;

__device__ inline float bf2f(unsigned short h) {
    return __uint_as_float((unsigned)h << 16);
}
__device__ inline unsigned short f2bf(float f) {
    unsigned u = __float_as_uint(f);
    return (unsigned short)((u + 0x7fffu + ((u >> 16) & 1u)) >> 16);   // RNE
}

// ---- accumulate one i8 row-chunk (16 bytes) with per-row scale ----------------
#define ACCQ(u, ss) {                                                            \
    int w0_ = (u).x, w1_ = (u).y, w2_ = (u).z, w3_ = (u).w;                      \
    a[ 0] += (float)(signed char)(w0_      ) * (ss);                             \
    a[ 1] += (float)(signed char)(w0_ >>  8) * (ss);                             \
    a[ 2] += (float)(signed char)(w0_ >> 16) * (ss);                             \
    a[ 3] += (float)(w0_ >> 24)              * (ss);                             \
    a[ 4] += (float)(signed char)(w1_      ) * (ss);                             \
    a[ 5] += (float)(signed char)(w1_ >>  8) * (ss);                             \
    a[ 6] += (float)(signed char)(w1_ >> 16) * (ss);                             \
    a[ 7] += (float)(w1_ >> 24)              * (ss);                             \
    a[ 8] += (float)(signed char)(w2_      ) * (ss);                             \
    a[ 9] += (float)(signed char)(w2_ >>  8) * (ss);                             \
    a[10] += (float)(signed char)(w2_ >> 16) * (ss);                             \
    a[11] += (float)(w2_ >> 24)              * (ss);                             \
    a[12] += (float)(signed char)(w3_      ) * (ss);                             \
    a[13] += (float)(signed char)(w3_ >>  8) * (ss);                             \
    a[14] += (float)(signed char)(w3_ >> 16) * (ss);                             \
    a[15] += (float)(w3_ >> 24)              * (ss); }

// ------- prep: x -> bf16 + i8(+scale), weights -> Bb, zero deg, init g ---------
// Row work: 16 lanes/row, each lane covers 8 features. Bb[o][k] row-major-in-k
// IS the MFMA B-fragment layout (n fixed, k contiguous).

__global__ __launch_bounds__(256) void cast_prep(
    const float* __restrict__ x,
    unsigned short* __restrict__ xb, signed char* __restrict__ xq,
    float* __restrict__ xs,
    const float* __restrict__ Wr0, const float* __restrict__ Wo0,
    const float* __restrict__ Wr1, const float* __restrict__ Wo1,
    const float* __restrict__ Wr2, const float* __restrict__ Wo2,
    unsigned short* __restrict__ B0, unsigned short* __restrict__ B1,
    unsigned short* __restrict__ B2,
    int* __restrict__ deg, float* __restrict__ g)
{
    int t = blockIdx.x * 256 + threadIdx.x;
    if (t < N_NODES * 16) {
        int node = t >> 4, ln = t & 15;
        const float4* xr = (const float4*)(x + (size_t)node * D + ln * 8);
        float4 v0 = xr[0], v1 = xr[1];
        float v[8] = {v0.x, v0.y, v0.z, v0.w, v1.x, v1.y, v1.z, v1.w};
        float am = 0.f;
#pragma unroll
        for (int i = 0; i < 8; ++i) am = fmaxf(am, fabsf(v[i]));
#pragma unroll
        for (int m = 1; m < 16; m <<= 1) am = fmaxf(am, __shfl_xor(am, m, 16));
        float inv = (am > 0.f) ? 127.f / am : 0.f;
        short8 hb;
#pragma unroll
        for (int i = 0; i < 8; ++i) hb[i] = (short)f2bf(v[i]);
        *(short8*)(xb + (size_t)node * D + ln * 8) = hb;
        int q0 = 0, q1 = 0;
#pragma unroll
        for (int i = 0; i < 4; ++i) { int q = (int)rintf(v[i]     * inv); q0 |= (q & 0xff) << (8 * i); }
#pragma unroll
        for (int i = 0; i < 4; ++i) { int q = (int)rintf(v[4 + i] * inv); q1 |= (q & 0xff) << (8 * i); }
        int2 qp; qp.x = q0; qp.y = q1;
        *(int2*)(xq + (size_t)node * D + ln * 8) = qp;
        if (ln == 0) xs[node] = am * (1.f / 127.f);
        return;
    }
    int w = t - N_NODES * 16;
    if (w < 3 * 128 * 256) {
        int l = w >> 15;
        int r = w & 32767;
        int o = r >> 8, k = r & 255;
        const float* Wr = (l == 0) ? Wr0 : (l == 1) ? Wr1 : Wr2;
        const float* Wo = (l == 0) ? Wo0 : (l == 1) ? Wo1 : Wo2;
        unsigned short* B = (l == 0) ? B0 : (l == 1) ? B1 : B2;
        float v = (k < 128) ? Wr[o * 128 + k] : Wo[o * 128 + (k - 128)];
        B[r] = f2bf(v);
        return;
    }
    w -= 3 * 128 * 256;
    if (w < N_NODES) { deg[w] = 0; return; }
    w -= N_NODES;
    if (w < N_GRAPHS * D) g[w] = -FLT_MAX;
}

// ---------------- CSR build (once per launch) ----------------------------------

__global__ void count_deg(const int* __restrict__ ei, int* __restrict__ deg) {
    int e = blockIdx.x * 256 + threadIdx.x;
    if (e < N_EDGES) atomicAdd(&deg[ei[N_EDGES + e]], 1);
}

__global__ __launch_bounds__(SCAN_T) void block_sum(const int* __restrict__ deg,
                                                    int* __restrict__ blockSums) {
    __shared__ int s[SCAN_T];
    int tid = threadIdx.x;
    int i = blockIdx.x * SCAN_T + tid;
    s[tid] = (i < N_NODES) ? deg[i] : 0;
    __syncthreads();
    for (int off = SCAN_T / 2; off > 0; off >>= 1) {
        if (tid < off) s[tid] += s[tid + off];
        __syncthreads();
    }
    if (tid == 0) blockSums[blockIdx.x] = s[0];
}

__global__ __launch_bounds__(SCAN_T) void scan_write(const int* __restrict__ deg,
                                                     const int* __restrict__ blockSums,
                                                     int* __restrict__ row_start,
                                                     int* __restrict__ cursor) {
    __shared__ int bs[SCAN_T];
    __shared__ int s[SCAN_T];
    int tid = threadIdx.x;
    bs[tid] = (tid < SCAN_NBLK) ? blockSums[tid] : 0;
    __syncthreads();
    for (int off = 1; off < SCAN_T; off <<= 1) {
        int tt = (tid >= off) ? bs[tid - off] : 0;
        __syncthreads();
        bs[tid] += tt;
        __syncthreads();
    }
    int myOff = (blockIdx.x == 0) ? 0 : bs[blockIdx.x - 1];
    if (blockIdx.x == 0 && tid == SCAN_T - 1) row_start[N_NODES] = bs[tid];

    int i = blockIdx.x * SCAN_T + tid;
    int v = (i < N_NODES) ? deg[i] : 0;
    s[tid] = v;
    __syncthreads();
    for (int off = 1; off < SCAN_T; off <<= 1) {
        int tt = (tid >= off) ? s[tid - off] : 0;
        __syncthreads();
        s[tid] += tt;
        __syncthreads();
    }
    if (i < N_NODES) {
        int rs = myOff + s[tid] - v;
        row_start[i] = rs;
        cursor[i]    = rs;
    }
}

__global__ void fill_csr(const int* __restrict__ ei, int* __restrict__ cursor,
                         int* __restrict__ csr_src) {
    int e = blockIdx.x * 256 + threadIdx.x;
    if (e < N_EDGES) {
        int dst = ei[N_EDGES + e];
        int pos = atomicAdd(&cursor[dst], 1);
        csr_src[pos] = ei[e];
    }
}

// ---------------- gather over i8 rows: one 128 B line per edge ------------------
// 8 lanes/node; lane ln covers features ln*16 .. +15 (16 i8 = one int4 load).
// Per-neighbor scale via FMA; f32 accumulate; bf16 agg out.

__global__ __launch_bounds__(256) void gather_q(
    const signed char* __restrict__ xq, const float* __restrict__ xs,
    const int* __restrict__ row_start, const int* __restrict__ csr_src,
    unsigned short* __restrict__ aggb)
{
    int grp  = threadIdx.x >> 3;              // 32 nodes per block
    int ln   = threadIdx.x & 7;
    int node = blockIdx.x * 32 + grp;
    if (node >= N_NODES) return;
    int beg = row_start[node];
    int end = row_start[node + 1];

    float a[16];
#pragma unroll
    for (int i = 0; i < 16; ++i) a[i] = 0.f;

    for (int base = beg; base < end; base += 8) {
        int n = end - base; if (n > 8) n = 8;
        int idx = (ln < n) ? csr_src[base + ln] : 0;   // one coalesced load
        int j = 0;
        for (; j + 3 < n; j += 4) {                    // 4 lines in flight / lane
            int s0 = __shfl(idx, j,     8); int s1 = __shfl(idx, j + 1, 8);
            int s2 = __shfl(idx, j + 2, 8); int s3 = __shfl(idx, j + 3, 8);
            int4 u0 = *(const int4*)(xq + (size_t)s0 * D + ln * 16);
            int4 u1 = *(const int4*)(xq + (size_t)s1 * D + ln * 16);
            int4 u2 = *(const int4*)(xq + (size_t)s2 * D + ln * 16);
            int4 u3 = *(const int4*)(xq + (size_t)s3 * D + ln * 16);
            float ss0 = xs[s0], ss1 = xs[s1], ss2 = xs[s2], ss3 = xs[s3];
            ACCQ(u0, ss0); ACCQ(u1, ss1); ACCQ(u2, ss2); ACCQ(u3, ss3);
        }
        for (; j < n; ++j) {
            int s0 = __shfl(idx, j, 8);
            int4 u0 = *(const int4*)(xq + (size_t)s0 * D + ln * 16);
            float ss0 = xs[s0];
            ACCQ(u0, ss0);
        }
    }
    short8 r0, r1;
#pragma unroll
    for (int i = 0; i < 8; ++i) { r0[i] = (short)f2bf(a[i]); r1[i] = (short)f2bf(a[8 + i]); }
    *(short8*)(aggb + (size_t)node * D + ln * 16)     = r0;
    *(short8*)(aggb + (size_t)node * D + ln * 16 + 8) = r1;
}

// ---------------- B staging: global -> LDS, MFMA-fragment order ----------------

__device__ inline void stage_b_half(unsigned short* sB, const unsigned short* __restrict__ Bb,
                                    int tid, int h) {
#pragma unroll
    for (int i = 0; i < 8; ++i) {
        int flat = tid + i * 256;            // 0..2047
        int fi = flat >> 6, ln = flat & 63;  // frag idx / lane
        int mm = ln & 15, qq = ln >> 4;
        int ksL = fi >> 3, tt = fi & 7;
        short8 v = *(const short8*)(Bb + (size_t)(tt * 16 + mm) * 256
                                    + (h * 4 + ksL) * 32 + qq * 8);
        *(short8*)(sB + (size_t)flat * 8) = v;
    }
}

// ---------------- MFMA GEMM: O = [agg|x] @ Bb^T + bias, relu -------------------
// Epilogue stages C through LDS, emits bf16 h + i8 h + per-row scale.

struct GemmShared {
    union {
        unsigned short b[16384];   // 32 KB B-half
        float c[64 * 130];         // 33.3 KB C tile
    };
};

__global__ __launch_bounds__(256) void gemm_mfma(
    const unsigned short* __restrict__ aggb, const unsigned short* __restrict__ xb,
    const unsigned short* __restrict__ Bb, const float* __restrict__ bias,
    unsigned short* __restrict__ Ob, signed char* __restrict__ Oq,
    float* __restrict__ Os)
{
    __shared__ GemmShared sh;
    int tid  = threadIdx.x;
    int wave = tid >> 6;
    int lane = tid & 63;
    int m    = lane & 15;
    int quad = lane >> 4;
    int row0 = blockIdx.x * 64 + wave * 16;

    int arow = row0 + m;
    if (arow > N_NODES - 1) arow = N_NODES - 1;

    short8 af[8];
#pragma unroll
    for (int ks = 0; ks < 8; ++ks) {
        const unsigned short* Asrc = (ks < 4) ? aggb : xb;
        af[ks] = *(const short8*)(Asrc + (size_t)arow * 128 + (ks & 3) * 32 + quad * 8);
    }

    floatx4 acc[8];
#pragma unroll
    for (int t = 0; t < 8; ++t) acc[t] = (floatx4){0.f, 0.f, 0.f, 0.f};

    stage_b_half(sh.b, Bb, tid, 0);
    __syncthreads();
#pragma unroll
    for (int ksL = 0; ksL < 4; ++ksL)
#pragma unroll
        for (int t = 0; t < 8; ++t) {
            short8 b = *(const short8*)(sh.b + (size_t)((ksL * 8 + t) * 64 + lane) * 8);
            acc[t] = __builtin_amdgcn_mfma_f32_16x16x32_bf16(af[ksL], b, acc[t], 0, 0, 0);
        }
    __syncthreads();
    stage_b_half(sh.b, Bb, tid, 1);
    __syncthreads();
#pragma unroll
    for (int ksL = 0; ksL < 4; ++ksL)
#pragma unroll
        for (int t = 0; t < 8; ++t) {
            short8 b = *(const short8*)(sh.b + (size_t)((ksL * 8 + t) * 64 + lane) * 8);
            acc[t] = __builtin_amdgcn_mfma_f32_16x16x32_bf16(af[4 + ksL], b, acc[t], 0, 0, 0);
        }
    __syncthreads();                         // all sB reads done; reuse as C tile

#pragma unroll
    for (int t = 0; t < 8; ++t) {
        int col = t * 16 + m;
        float bv = bias[col];
#pragma unroll
        for (int r = 0; r < 4; ++r) {
            float v = fmaxf(acc[t][r] + bv, 0.f);          // relu (layers 1,2)
            sh.c[(wave * 16 + quad * 4 + r) * 130 + col] = v;
        }
    }
    __syncthreads();

    // quant + store: 4 threads/row, 32 cols each (contiguous)
    int lr  = tid >> 2;
    int seg = tid & 3;
    int grow = blockIdx.x * 64 + lr;
    const float* cp = &sh.c[lr * 130 + seg * 32];
    float vv[32];
    float am = 0.f;
#pragma unroll
    for (int i = 0; i < 32; ++i) { vv[i] = cp[i]; am = fmaxf(am, fabsf(vv[i])); }
    am = fmaxf(am, __shfl_xor(am, 1));
    am = fmaxf(am, __shfl_xor(am, 2));
    float inv = (am > 0.f) ? 127.f / am : 0.f;

    if (grow < N_NODES) {
#pragma unroll
        for (int c8 = 0; c8 < 4; ++c8) {
            short8 hb;
#pragma unroll
            for (int i = 0; i < 8; ++i) hb[i] = (short)f2bf(vv[c8 * 8 + i]);
            *(short8*)(Ob + (size_t)grow * 128 + seg * 32 + c8 * 8) = hb;
        }
        int qd[8];
#pragma unroll
        for (int d = 0; d < 8; ++d) {
            int q = 0;
#pragma unroll
            for (int i = 0; i < 4; ++i) {
                int qq = (int)rintf(vv[d * 4 + i] * inv);
                q |= (qq & 0xff) << (8 * i);
            }
            qd[d] = q;
        }
        int4 p0; p0.x = qd[0]; p0.y = qd[1]; p0.z = qd[2]; p0.w = qd[3];
        int4 p1; p1.x = qd[4]; p1.y = qd[5]; p1.z = qd[6]; p1.w = qd[7];
        *(int4*)(Oq + (size_t)grow * 128 + seg * 32)      = p0;
        *(int4*)(Oq + (size_t)grow * 128 + seg * 32 + 16) = p1;
        if (seg == 0) Os[grow] = am * (1.f / 127.f);
    }
}

// ---------------- layer-3 GEMM with fused pooled max ---------------------------

struct PoolShared {
    union {
        unsigned short b[16384];     // 32 KB B-half
        float c[64 * 129];           // 33 KB C tile
    };
};

__global__ __launch_bounds__(256) void gemm_pool(
    const unsigned short* __restrict__ aggb, const unsigned short* __restrict__ xb,
    const unsigned short* __restrict__ Bb, const float* __restrict__ bias,
    const int* __restrict__ batch, float* __restrict__ g)
{
    __shared__ PoolShared sh;
    __shared__ int bl[64];
    int tid  = threadIdx.x;
    int wave = tid >> 6;
    int lane = tid & 63;
    int m    = lane & 15;
    int quad = lane >> 4;
    int row0 = blockIdx.x * 64;

    int arow = row0 + wave * 16 + m;
    if (arow > N_NODES - 1) arow = N_NODES - 1;

    short8 af[8];
#pragma unroll
    for (int ks = 0; ks < 8; ++ks) {
        const unsigned short* Asrc = (ks < 4) ? aggb : xb;
        af[ks] = *(const short8*)(Asrc + (size_t)arow * 128 + (ks & 3) * 32 + quad * 8);
    }

    floatx4 acc[8];
#pragma unroll
    for (int t = 0; t < 8; ++t) acc[t] = (floatx4){0.f, 0.f, 0.f, 0.f};

    if (tid < 64) {
        int grow = row0 + tid;
        bl[tid] = (grow < N_NODES) ? batch[grow] : -1;
    }
    stage_b_half(sh.b, Bb, tid, 0);
    __syncthreads();
#pragma unroll
    for (int ksL = 0; ksL < 4; ++ksL)
#pragma unroll
        for (int t = 0; t < 8; ++t) {
            short8 b = *(const short8*)(sh.b + (size_t)((ksL * 8 + t) * 64 + lane) * 8);
            acc[t] = __builtin_amdgcn_mfma_f32_16x16x32_bf16(af[ksL], b, acc[t], 0, 0, 0);
        }
    __syncthreads();
    stage_b_half(sh.b, Bb, tid, 1);
    __syncthreads();
#pragma unroll
    for (int ksL = 0; ksL < 4; ++ksL)
#pragma unroll
        for (int t = 0; t < 8; ++t) {
            short8 b = *(const short8*)(sh.b + (size_t)((ksL * 8 + t) * 64 + lane) * 8);
            acc[t] = __builtin_amdgcn_mfma_f32_16x16x32_bf16(af[4 + ksL], b, acc[t], 0, 0, 0);
        }
    __syncthreads();                         // all sB reads done; reuse as C tile

#pragma unroll
    for (int t = 0; t < 8; ++t) {
        int col = t * 16 + m;
        float bv = bias[col];
#pragma unroll
        for (int r = 0; r < 4; ++r)
            sh.c[(wave * 16 + quad * 4 + r) * 129 + col] = acc[t][r] + bv;
    }
    __syncthreads();

    int nvalid = min(64, N_NODES - row0);
    int b0 = bl[0], b1 = bl[nvalid - 1];     // batch sorted; 1-3 graphs per block
    int col  = tid & 127;
    int rbeg = (tid >> 7) * 32;
    for (int gg = b0; gg <= b1; ++gg) {
        float cur = -FLT_MAX;
#pragma unroll
        for (int r = 0; r < 32; ++r) {
            int rr = rbeg + r;
            float v = (bl[rr] == gg) ? sh.c[rr * 129 + col] : -FLT_MAX;
            cur = fmaxf(cur, v);
        }
        if (cur > -FLT_MAX) {
            float* ad = &g[gg * D + col];
            if (cur >= 0.f) atomicMax((int*)ad, __float_as_int(cur));
            else            atomicMin((unsigned int*)ad, __float_as_uint(cur));
        }
    }
}

// ---------------- head: one wave per graph -------------------------------------

__global__ __launch_bounds__(64) void mlp_head(const float* __restrict__ g,
                         const float* __restrict__ W1, const float* __restrict__ b1,
                         const float* __restrict__ W2, const float* __restrict__ b2,
                         float* __restrict__ out) {
    int gi = blockIdx.x;
    int lane = threadIdx.x;
    float x0 = g[gi * D + lane];
    float x1 = g[gi * D + 64 + lane];
    float o = b2[0];
#pragma unroll
    for (int j = 0; j < 5; ++j) {
        float p = x0 * W1[j * D + lane] + x1 * W1[j * D + 64 + lane];
#pragma unroll
        for (int off = 32; off > 0; off >>= 1) p += __shfl_xor(p, off, 64);
        o += fmaxf(p + b1[j], 0.f) * W2[j];
    }
    if (lane == 0) out[gi] = o;
}

extern "C" void kernel_launch(void* const* d_in, const int* in_sizes, int n_in,
                              void* d_out, int out_size, void* d_ws, size_t ws_size,
                              hipStream_t stream) {
    const float* x     = (const float*)d_in[0];
    const int*   ei    = (const int*)d_in[1];
    const int*   batch = (const int*)d_in[2];
    const float* Wrel[3]  = {(const float*)d_in[3], (const float*)d_in[6], (const float*)d_in[9]};
    const float* brel[3]  = {(const float*)d_in[4], (const float*)d_in[7], (const float*)d_in[10]};
    const float* Wroot[3] = {(const float*)d_in[5], (const float*)d_in[8], (const float*)d_in[11]};
    const float* W1 = (const float*)d_in[12];
    const float* b1 = (const float*)d_in[13];
    const float* W2 = (const float*)d_in[14];
    const float* b2 = (const float*)d_in[15];
    float* out = (float*)d_out;

    char* ws = (char*)d_ws;
    const size_t nodeB16 = (size_t)N_NODES * D * sizeof(unsigned short);   // 12.8 MB
    const size_t nodeB8  = (size_t)N_NODES * D;                            // 6.4 MB
    unsigned short* xb   = (unsigned short*)(ws);
    unsigned short* h1b  = (unsigned short*)(ws + 1 * nodeB16);
    unsigned short* h2b  = (unsigned short*)(ws + 2 * nodeB16);
    unsigned short* aggb = (unsigned short*)(ws + 3 * nodeB16);
    char* p = ws + 4 * nodeB16;
    signed char* xq  = (signed char*)p;  p += nodeB8;
    signed char* h1q = (signed char*)p;  p += nodeB8;
    signed char* h2q = (signed char*)p;  p += nodeB8;
    float* xs  = (float*)p;  p += N_NODES * sizeof(float);
    float* h1s = (float*)p;  p += N_NODES * sizeof(float);
    float* h2s = (float*)p;  p += N_NODES * sizeof(float);
    unsigned short* Bb0 = (unsigned short*)p;   p += 128 * 256 * sizeof(unsigned short);
    unsigned short* Bb1 = (unsigned short*)p;   p += 128 * 256 * sizeof(unsigned short);
    unsigned short* Bb2 = (unsigned short*)p;   p += 128 * 256 * sizeof(unsigned short);
    float* g        = (float*)p;                p += N_GRAPHS * D * sizeof(float);
    int*   deg      = (int*)p;                  p += N_NODES * sizeof(int);
    int*   row_start= (int*)p;                  p += (N_NODES + 1) * sizeof(int);
    int*   cursor   = (int*)p;                  p += N_NODES * sizeof(int);
    int*   csr_src  = (int*)p;                  p += N_EDGES * sizeof(int);
    int*   blockSums= (int*)p;                  p += SCAN_NBLK * sizeof(int);

    // prep: bf16 + i8 casts, weight packs, zero deg, init g
    const int cast_total = N_NODES * 16 + 3 * 128 * 256 + N_NODES + N_GRAPHS * D;
    cast_prep<<<(cast_total + 255) / 256, 256, 0, stream>>>(
        x, xb, xq, xs,
        Wrel[0], Wroot[0], Wrel[1], Wroot[1], Wrel[2], Wroot[2],
        Bb0, Bb1, Bb2, deg, g);

    // CSR build (once per call)
    count_deg<<<(N_EDGES + 255) / 256, 256, 0, stream>>>(ei, deg);
    block_sum<<<SCAN_NBLK, SCAN_T, 0, stream>>>(deg, blockSums);
    scan_write<<<SCAN_NBLK, SCAN_T, 0, stream>>>(deg, blockSums, row_start, cursor);
    fill_csr<<<(N_EDGES + 255) / 256, 256, 0, stream>>>(ei, cursor, csr_src);

    const int ggrid = (N_NODES + 31) / 32;                // 1563
    const int mgrid = (N_NODES + 63) / 64;                // 782

    // layer 1
    gather_q<<<ggrid, 256, 0, stream>>>(xq, xs, row_start, csr_src, aggb);
    gemm_mfma<<<mgrid, 256, 0, stream>>>(aggb, xb, Bb0, brel[0], h1b, h1q, h1s);
    // layer 2
    gather_q<<<ggrid, 256, 0, stream>>>(h1q, h1s, row_start, csr_src, aggb);
    gemm_mfma<<<mgrid, 256, 0, stream>>>(aggb, h1b, Bb1, brel[1], h2b, h2q, h2s);
    // layer 3 + pool
    gather_q<<<ggrid, 256, 0, stream>>>(h2q, h2s, row_start, csr_src, aggb);
    gemm_pool<<<mgrid, 256, 0, stream>>>(aggb, h2b, Bb2, brel[2], batch, g);

    mlp_head<<<N_GRAPHS, 64, 0, stream>>>(g, W1, b1, W2, b2, out);
}